// Round 7
// baseline (298.713 us; speedup 1.0000x reference)
//
#include <hip/hip_runtime.h>
#include <hip/hip_bf16.h>
#include <stdint.h>

// Problem constants
#define BB 2
#define SS 2048
#define HIDD 2048
#define NHH 16
#define HDD 128
#define NROWS (BB*SS)        // 4096
#define QKVN (3*HIDD)        // 6144
// 1/sqrt(128) * log2(e): scores land in log2 domain -> exp2 in softmax
#define SCALE_QL2 (0.08838834764831845f * 1.4426950408889634f)

typedef float f32x4 __attribute__((ext_vector_type(4)));
typedef short s16x8 __attribute__((ext_vector_type(8)));
typedef uint32_t u32;
typedef __attribute__((address_space(1))) const u32 gau32;
typedef __attribute__((address_space(3))) u32 lau32;

__device__ __forceinline__ ushort f2bf(float f) {
    u32 u = __builtin_bit_cast(u32, f);
    u32 r = (u + 0x7fffu + ((u >> 16) & 1u)) >> 16;
    return (ushort)r;
}
__device__ __forceinline__ float bf2f(ushort h) {
    u32 u = ((u32)h) << 16;
    return __builtin_bit_cast(float, u);
}
__device__ __forceinline__ u32 cvtpk(float lo, float hi) {
    u32 r;
    asm("v_cvt_pk_bf16_f32 %0, %1, %2" : "=v"(r) : "v"(lo), "v"(hi));
    return r;
}
#define EXP2(x) __builtin_amdgcn_exp2f(x)

#define GL_LDS(s, d) __builtin_amdgcn_global_load_lds((gau32*)(s), (lau32*)(d), 16, 0, 0)
#define BAR() __builtin_amdgcn_s_barrier()
#define SCB() __builtin_amdgcn_sched_barrier(0)
#define VMW(n) { asm volatile("s_waitcnt vmcnt(" #n ")" ::: "memory"); SCB(); }

// ---------------- fp32 -> bf16 convert (vectorized, grid-stride) ----------
__global__ __launch_bounds__(256) void cvt_f32_bf16(const float* __restrict__ in,
                                                    ushort* __restrict__ out, int n4) {
    int i = blockIdx.x * 256 + threadIdx.x;
    int stride = gridDim.x * 256;
    for (; i < n4; i += stride) {
        float4 v = ((const float4*)in)[i];
        ushort4 o;
        o.x = f2bf(v.x); o.y = f2bf(v.y); o.z = f2bf(v.z); o.w = f2bf(v.w);
        ((ushort4*)out)[i] = o;
    }
}

// ---------------- RoPE cos/sin table: [2048][64] float2 ------------------
__global__ __launch_bounds__(256) void rope_table_k(float2* __restrict__ tab) {
    int idx = blockIdx.x * 256 + threadIdx.x;
    if (idx >= SS * 64) return;
    int j = idx & 63;
    int s = idx >> 6;
    float e = -(float)j * (13.287712379549449f / 64.0f);
    float inv = exp2f(e);
    float ang = (float)s * inv;
    float sv, cv;
    sincosf(ang, &sv, &cv);
    tab[idx] = make_float2(cv, sv);
}

// ---------------- RoPE apply in-place on bf16 QKV; emit fp32 K out -------
__global__ __launch_bounds__(256) void rope_apply_k(ushort* __restrict__ qkv,
                                                    const float2* __restrict__ tab,
                                                    float* __restrict__ kout) {
    int p = blockIdx.x * 256 + threadIdx.x;
    if (p >= NROWS * 2 * NHH * 64) return;
    int j  = p & 63;
    int h  = (p >> 6) & 15;
    int w  = (p >> 10) & 1;   // 0=q, 1=k
    int bs = p >> 11;
    int s  = bs & (SS - 1);
    size_t off = (size_t)bs * QKVN + (size_t)w * HIDD + h * HDD + 2 * j;
    u32 pr = *(const u32*)(qkv + off);
    float x1 = bf2f((ushort)(pr & 0xffffu));
    float x2 = bf2f((ushort)(pr >> 16));
    float2 cs = tab[s * 64 + j];
    float r1 = x1 * cs.x - x2 * cs.y;
    float r2 = x1 * cs.y + x2 * cs.x;
    if (w == 0) {            // fold score scale AND log2(e) into Q
        r1 *= SCALE_QL2; r2 *= SCALE_QL2;
    } else {                 // K: also write fp32 output (unscaled)
        float* ko = kout + ((size_t)bs * NHH + h) * HDD + 2 * j;
        ko[0] = r1; ko[1] = r2;
    }
    u32 op = (u32)f2bf(r1) | ((u32)f2bf(r2) << 16);
    *(u32*)(qkv + off) = op;
}

// ---------------- V transpose: qkv V section -> VT[b][h][d][s] -----------
__global__ __launch_bounds__(256) void vtrans_k(const ushort* __restrict__ qkv,
                                                ushort* __restrict__ vt) {
    __shared__ ushort tile[64 * 66];
    int bid = blockIdx.x;              // 2048 = 32 bh * 32 st * 2 dt
    int dt = bid & 1, st = (bid >> 1) & 31, bh = bid >> 6;
    int b = bh >> 4, h = bh & 15;
    int s0 = st * 64, d0 = dt * 64;
    int tid = threadIdx.x;
    #pragma unroll
    for (int i = 0; i < 2; ++i) {
        int idx = tid + i * 256;
        int row = idx >> 3, c8 = idx & 7;
        const ushort* src = qkv + (size_t)(b * SS + s0 + row) * QKVN + 2 * HIDD + h * HDD + d0 + c8 * 8;
        uint4 v = *(const uint4*)src;
        const u32* vw = (const u32*)&v;
        u32* dst = (u32*)((char*)tile + row * 132 + c8 * 16);
        dst[0] = vw[0]; dst[1] = vw[1]; dst[2] = vw[2]; dst[3] = vw[3];
    }
    __syncthreads();
    #pragma unroll
    for (int i = 0; i < 2; ++i) {
        int idx = tid + i * 256;
        int d = idx >> 3, sc8 = idx & 7;
        u32 wv[4];
        #pragma unroll
        for (int k = 0; k < 4; ++k) {
            ushort a = tile[(sc8 * 8 + 2 * k) * 66 + d];
            ushort c = tile[(sc8 * 8 + 2 * k + 1) * 66 + d];
            wv[k] = (u32)a | ((u32)c << 16);
        }
        ushort* dst = vt + ((size_t)(b * NHH + h) * HDD + d0 + d) * SS + s0 + sc8 * 8;
        *(uint4*)dst = *(const uint4*)wv;
    }
}

// ---------------- 128x256-tile GEMM, C = A * B^T, K=2048 -----------------
// 8 waves (2M x 4N), per-wave out 64x64, BK=64, LDS 96KB double-buffered.
// XCD-locality swizzle v2: XCD x owns N-columns [x*cpx, (x+1)*cpx), iterates
// M-major -> per-XCD concurrent working set = cpx B-panels (cpx MB, L2-fits)
// x all M A-panels (shared by cpx concurrent blocks). B fetched once/device.
#define SA2(bb, kc) { const ushort* _s = Ab + (size_t)(kc) + off0; \
    GL_LDS(_s,            smem + (bb) * 49152 + w * 1024); \
    GL_LDS(_s + 64 * 2048, smem + (bb) * 49152 + 8192 + w * 1024); }
#define SB4(bb, kc) { const ushort* _s = Bb + (size_t)(kc) + off0; \
    GL_LDS(_s,             smem + (bb) * 49152 + 16384 + w * 1024); \
    GL_LDS(_s + 64 * 2048,  smem + (bb) * 49152 + 24576 + w * 1024); \
    GL_LDS(_s + 128 * 2048, smem + (bb) * 49152 + 32768 + w * 1024); \
    GL_LDS(_s + 192 * 2048, smem + (bb) * 49152 + 40960 + w * 1024); }
#define RDA(dst, bb, kk) { const char* _p = smem + (bb) * 49152 + aoff; \
    _Pragma("unroll") for (int f = 0; f < 4; ++f) \
        dst[f] = *(const s16x8*)(_p + f * 2048 + (colr ^ ((kk) << 6))); }
#define RDB(dst, bb, kk) { const char* _p = smem + (bb) * 49152 + 16384 + boff; \
    _Pragma("unroll") for (int n = 0; n < 4; ++n) \
        dst[n] = *(const s16x8*)(_p + n * 2048 + (colr ^ ((kk) << 6))); }
#define MMX(aa, bb2) { __builtin_amdgcn_s_setprio(1); \
    _Pragma("unroll") for (int f = 0; f < 4; ++f) \
        _Pragma("unroll") for (int n = 0; n < 4; ++n) \
            acc[f][n] = __builtin_amdgcn_mfma_f32_16x16x32_bf16( \
                aa[f], bb2[n], acc[f][n], 0, 0, 0); \
    __builtin_amdgcn_s_setprio(0); }

template<int OUTF32>
__global__ __launch_bounds__(512) void gemm128(const ushort* __restrict__ A,
                                               const ushort* __restrict__ Bm,
                                               void* __restrict__ Cv, int N) {
    __shared__ char smem[98304];
    const int tid = threadIdx.x;
    const int w = tid >> 6, lane = tid & 63;
    const int wr = w >> 2, wc = w & 3;           // 2M x 4N waves
    const int l16 = lane & 15, lq = lane >> 4;

    // XCD-locality swizzle v2 (requires nbn % 8 == 0)
    const int nbn = N >> 8;                       // N-tiles (24 or 8)
    const int nbm = gridDim.x / nbn;              // M-tiles (32)
    const int cpx = nbn >> 3;                     // N-cols per XCD (3 or 1)
    const int xcd = blockIdx.x & 7;
    const int idx = blockIdx.x >> 3;              // 0 .. nbm*cpx-1
    const int bn_t = xcd * cpx + idx / nbm;
    const int bm_t = idx % nbm;
    const int bm0 = bm_t << 7, bn0 = bn_t << 8;

    const ushort* Ab = A + (size_t)bm0 * 2048;
    const ushort* Bb = Bm + (size_t)bn0 * 2048;

    // stage: rows chunk*64 + w*8 + (lane>>3), pre-swizzled column
    const int colu = ((lane & 7) ^ ((lane >> 3) & 7)) << 3;         // ushorts
    const u32 off0 = (u32)((w * 8 + (lane >> 3)) * 2048 + colu);
    // read addressing
    const int colr = (lq << 4) ^ ((l16 & 7) << 4);                  // bytes
    const int aoff = wr * 8192 + l16 * 128;
    const int boff = wc * 8192 + l16 * 128;

    f32x4 acc[4][4] = {};
    s16x8 a0[4], a1[4], b0[4], b1[4];

    // prologue: stage tile 0 into buf0 (6 loads)
    SA2(0, 0); SB4(0, 0);

    for (int t = 0; t < 32; ++t) {
        const int cur = t & 1;
        const int kcn = ((t + 1) & 31) * 64;
        SA2(cur ^ 1, kcn);                 // 2 gloads for next tile
        VMW(2); BAR(); SCB();              // cur fully staged (all waves)
        RDA(a0, cur, 0); RDB(b0, cur, 0);
        RDA(a1, cur, 1); RDB(b1, cur, 1);  // 16 ds_reads
        SB4(cur ^ 1, kcn);                 // 4 gloads for next tile
        MMX(a0, b0);                       // compiler inserts lgkm waits
        MMX(a1, b1);
        SCB(); BAR();                      // all waves done reading cur
    }

    // epilogue
    #pragma unroll
    for (int f = 0; f < 4; ++f)
        #pragma unroll
        for (int n = 0; n < 4; ++n) {
            int row = bm0 + wr * 64 + f * 16 + lq * 4;
            int col = bn0 + wc * 64 + n * 16 + l16;
            if (OUTF32) {
                float* C = (float*)Cv;
                #pragma unroll
                for (int r = 0; r < 4; ++r)
                    C[(size_t)(row + r) * N + col] = acc[f][n][r];
            } else {
                ushort* C = (ushort*)Cv;
                #pragma unroll
                for (int r = 0; r < 4; ++r)
                    C[(size_t)(row + r) * N + col] = f2bf(acc[f][n][r]);
            }
        }
}

// ---------------- Flash attention (v3: log2 softmax, defer-max, cvt_pk) --
__global__ __launch_bounds__(256, 2) void attn_k(const ushort* __restrict__ qkv,
                                                 const ushort* __restrict__ vt,
                                                 ushort* __restrict__ aout) {
    extern __shared__ char asmem[];

    const int bid = blockIdx.x;
    const int L = (bid & 7) * 64 + (bid >> 3);
    const int qt = L & 15, bh = L >> 4;
    const int b = bh >> 4, h = bh & 15;
    const int tid = threadIdx.x;
    const int w = tid >> 6, lane = tid & 63;
    const int l16 = lane & 15, lq = lane >> 4;

    s16x8 qf[2][4];
    #pragma unroll
    for (int qb = 0; qb < 2; ++qb) {
        size_t qbase = (size_t)(b * SS + qt * 128 + w * 32 + qb * 16 + l16) * QKVN + h * HDD;
        #pragma unroll
        for (int kk = 0; kk < 4; ++kk)
            qf[qb][kk] = *(const s16x8*)(qkv + qbase + kk * 32 + lq * 8);
    }

    const ushort* ksrc[4];
    const ushort* vsrc[4];
    #pragma unroll
    for (int i = 0; i < 4; ++i) {
        int krow = w * 16 + i * 4 + (lane >> 4);
        int kcolb = ((lane & 15) * 16) ^ ((krow & 7) << 4);
        ksrc[i] = qkv + (size_t)(b * SS + krow) * QKVN + HIDD + h * HDD + kcolb / 2;
        int drow = w * 32 + i * 8 + (lane >> 3);
        int vcolb = ((lane & 7) * 16) ^ ((drow & 7) << 4);
        vsrc[i] = vt + ((size_t)(b * NHH + h) * HDD + drow) * SS + vcolb / 2;
    }

    f32x4 accO[2][8] = {};
    float mrow[2] = {-3e38f, -3e38f};
    float lrow[2] = {0.f, 0.f};

    char* Pb = asmem + 65536 + w * 4096;
    const int kswz = (l16 & 7) << 4;
    const int pswz = (l16 & 3) << 5;

    {
        char* kb = asmem + w * 4096;
        char* vb = asmem + 32768 + w * 4096;
        #pragma unroll
        for (int i = 0; i < 4; ++i) {
            GL_LDS(ksrc[i], kb + i * 1024); ksrc[i] += 64 * QKVN;
            GL_LDS(vsrc[i], vb + i * 1024); vsrc[i] += 64;
        }
    }
    __syncthreads();

    for (int t = 0; t < 32; ++t) {
        const int cur = t & 1;
        if (t < 31) {
            char* kb = asmem + (cur ^ 1) * 16384 + w * 4096;
            char* vb = asmem + 32768 + (cur ^ 1) * 16384 + w * 4096;
            #pragma unroll
            for (int i = 0; i < 4; ++i) {
                GL_LDS(ksrc[i], kb + i * 1024); ksrc[i] += 64 * QKVN;
                GL_LDS(vsrc[i], vb + i * 1024); vsrc[i] += 64;
            }
        }
        const char* Kb = asmem + cur * 16384;
        const char* Vb = asmem + 32768 + cur * 16384;

        // S^T = K . Q  (scores already in log2 domain via Q pre-scale)
        f32x4 sc[2][4] = {};
        #pragma unroll
        for (int nb = 0; nb < 4; ++nb) {
            int rbase = (nb * 16 + l16) * 256;
            #pragma unroll
            for (int kk = 0; kk < 4; ++kk) {
                s16x8 kf = *(const s16x8*)(Kb + rbase + ((kk * 64 + lq * 16) ^ kswz));
                sc[0][nb] = __builtin_amdgcn_mfma_f32_16x16x32_bf16(kf, qf[0][kk], sc[0][nb], 0, 0, 0);
                sc[1][nb] = __builtin_amdgcn_mfma_f32_16x16x32_bf16(kf, qf[1][kk], sc[1][nb], 0, 0, 0);
            }
        }

        // online softmax with defer-max (T13): row = q = qb*16+l16
        float pmax[2];
        #pragma unroll
        for (int qb = 0; qb < 2; ++qb) {
            float m0 = fmaxf(fmaxf(fmaxf(sc[qb][0][0], sc[qb][0][1]), fmaxf(sc[qb][0][2], sc[qb][0][3])),
                             fmaxf(fmaxf(sc[qb][1][0], sc[qb][1][1]), fmaxf(sc[qb][1][2], sc[qb][1][3])));
            m0 = fmaxf(m0, fmaxf(fmaxf(fmaxf(sc[qb][2][0], sc[qb][2][1]), fmaxf(sc[qb][2][2], sc[qb][2][3])),
                                 fmaxf(fmaxf(sc[qb][3][0], sc[qb][3][1]), fmaxf(sc[qb][3][2], sc[qb][3][3]))));
            m0 = fmaxf(m0, __shfl_xor(m0, 16));
            m0 = fmaxf(m0, __shfl_xor(m0, 32));
            pmax[qb] = m0;
        }
        #pragma unroll
        for (int qb = 0; qb < 2; ++qb) {
            if (__all(pmax[qb] - mrow[qb] <= 8.0f)) {
                float mm = mrow[qb];
                float s = 0.f;
                #pragma unroll
                for (int nb = 0; nb < 4; ++nb)
                    #pragma unroll
                    for (int r = 0; r < 4; ++r) {
                        float pv = EXP2(sc[qb][nb][r] - mm);
                        sc[qb][nb][r] = pv;
                        s += pv;
                    }
                s += __shfl_xor(s, 16);
                s += __shfl_xor(s, 32);
                lrow[qb] += s;
            } else {
                float mnew = fmaxf(mrow[qb], pmax[qb]);
                float sclv = EXP2(mrow[qb] - mnew);
                mrow[qb] = mnew;
                float s = 0.f;
                #pragma unroll
                for (int nb = 0; nb < 4; ++nb)
                    #pragma unroll
                    for (int r = 0; r < 4; ++r) {
                        float pv = EXP2(sc[qb][nb][r] - mnew);
                        sc[qb][nb][r] = pv;
                        s += pv;
                    }
                s += __shfl_xor(s, 16);
                s += __shfl_xor(s, 32);
                lrow[qb] = lrow[qb] * sclv + s;
                #pragma unroll
                for (int r = 0; r < 4; ++r) {
                    float sr = __shfl(sclv, lq * 4 + r);
                    #pragma unroll
                    for (int ob = 0; ob < 8; ++ob)
                        accO[qb][ob][r] *= sr;
                }
            }
        }

        // P -> per-wave swizzled LDS via v_cvt_pk_bf16_f32
        #pragma unroll
        for (int qb = 0; qb < 2; ++qb) {
            int qrow = (qb * 16 + l16) * 128;
            #pragma unroll
            for (int nb = 0; nb < 4; ++nb) {
                uint2 v2 = make_uint2(cvtpk(sc[qb][nb][0], sc[qb][nb][1]),
                                      cvtpk(sc[qb][nb][2], sc[qb][nb][3]));
                *(uint2*)(Pb + qrow + ((nb * 32 + lq * 8) ^ pswz)) = v2;
            }
        }

        // O += P . V
        #pragma unroll
        for (int kk2 = 0; kk2 < 2; ++kk2) {
            int cb = (kk2 * 64 + lq * 16);
            s16x8 pf0 = *(const s16x8*)(Pb + l16 * 128 + (cb ^ pswz));
            s16x8 pf1 = *(const s16x8*)(Pb + (16 + l16) * 128 + (cb ^ pswz));
            #pragma unroll
            for (int ob = 0; ob < 8; ++ob) {
                int d = ob * 16 + l16;
                s16x8 vf = *(const s16x8*)(Vb + d * 128 + (cb ^ ((d & 7) << 4)));
                accO[0][ob] = __builtin_amdgcn_mfma_f32_16x16x32_bf16(pf0, vf, accO[0][ob], 0, 0, 0);
                accO[1][ob] = __builtin_amdgcn_mfma_f32_16x16x32_bf16(pf1, vf, accO[1][ob], 0, 0, 0);
            }
        }
        __syncthreads();
    }

    float inv0 = 1.f / lrow[0], inv1 = 1.f / lrow[1];
    #pragma unroll
    for (int r = 0; r < 4; ++r) {
        float i0 = __shfl(inv0, lq * 4 + r);
        float i1 = __shfl(inv1, lq * 4 + r);
        int row0 = b * SS + qt * 128 + w * 32 + lq * 4 + r;
        #pragma unroll
        for (int ob = 0; ob < 8; ++ob) {
            int col = h * HDD + ob * 16 + l16;
            aout[(size_t)row0 * HIDD + col] = f2bf(accO[0][ob][r] * i0);
            aout[(size_t)(row0 + 16) * HIDD + col] = f2bf(accO[1][ob][r] * i1);
        }
    }
}

// ---------------- launch -------------------------------------------------
extern "C" void kernel_launch(void* const* d_in, const int* in_sizes, int n_in,
                              void* d_out, int out_size, void* d_ws, size_t ws_size,
                              hipStream_t stream) {
    const float* x     = (const float*)d_in[0];
    const float* w_qkv = (const float*)d_in[1];
    const float* w_out = (const float*)d_in[2];
    float* out = (float*)d_out;

    char* ws = (char*)d_ws;
    ushort* qkv_bf  = (ushort*)(ws);
    ushort* xbf     = (ushort*)(ws + 50331648);
    ushort* wq_bf   = (ushort*)(ws + 67108864);
    ushort* vtbuf   = (ushort*)(ws + 67108864);
    ushort* wout_bf = (ushort*)(ws + 67108864 + 16777216);
    float2* tab     = (float2*)(ws + 92274688);

    cvt_f32_bf16<<<2048, 256, 0, stream>>>(x, xbf, (NROWS * HIDD) / 4);
    cvt_f32_bf16<<<2048, 256, 0, stream>>>(w_qkv, wq_bf, (QKVN * HIDD) / 4);
    rope_table_k<<<(SS * 64) / 256, 256, 0, stream>>>(tab);

    // QKV projection: 128x256 tiles -> 32*24 = 768 blocks (3/CU exact)
    gemm128<0><<<(NROWS / 128) * (QKVN / 256), 512, 0, stream>>>(xbf, wq_bf, qkv_bf, QKVN);

    rope_apply_k<<<(NROWS * 2 * NHH * 64) / 256, 256, 0, stream>>>(qkv_bf, tab,
                                                                   out + (size_t)NROWS * HIDD);
    vtrans_k<<<2048, 256, 0, stream>>>(qkv_bf, vtbuf);
    cvt_f32_bf16<<<2048, 256, 0, stream>>>(w_out, wout_bf, (HIDD * HIDD) / 4);

    attn_k<<<512, 256, 81920, stream>>>(qkv_bf, vtbuf, xbf);

    // output projection: 32*8 = 256 blocks (1/CU exact), fp32 out
    gemm128<1><<<(NROWS / 128) * (HIDD / 256), 512, 0, stream>>>(xbf, wout_bf, out, HIDD);
}

// Round 8
// 293.853 us; speedup vs baseline: 1.0165x; 1.0165x over previous
//
#include <hip/hip_runtime.h>
#include <hip/hip_bf16.h>
#include <stdint.h>

// Problem constants
#define BB 2
#define SS 2048
#define HIDD 2048
#define NHH 16
#define HDD 128
#define NROWS (BB*SS)        // 4096
#define QKVN (3*HIDD)        // 6144
// 1/sqrt(128) * log2(e): scores land in log2 domain -> exp2 in softmax
#define SCALE_QL2 (0.08838834764831845f * 1.4426950408889634f)

typedef float f32x4 __attribute__((ext_vector_type(4)));
typedef short s16x8 __attribute__((ext_vector_type(8)));
typedef uint32_t u32;
typedef __attribute__((address_space(1))) const u32 gau32;
typedef __attribute__((address_space(3))) u32 lau32;

__device__ __forceinline__ ushort f2bf(float f) {
    u32 u = __builtin_bit_cast(u32, f);
    u32 r = (u + 0x7fffu + ((u >> 16) & 1u)) >> 16;
    return (ushort)r;
}
__device__ __forceinline__ float bf2f(ushort h) {
    u32 u = ((u32)h) << 16;
    return __builtin_bit_cast(float, u);
}
__device__ __forceinline__ u32 cvtpk(float lo, float hi) {
    u32 r;
    asm("v_cvt_pk_bf16_f32 %0, %1, %2" : "=v"(r) : "v"(lo), "v"(hi));
    return r;
}
#define EXP2(x) __builtin_amdgcn_exp2f(x)

#define GL_LDS(s, d) __builtin_amdgcn_global_load_lds((gau32*)(s), (lau32*)(d), 16, 0, 0)
#define BAR() __builtin_amdgcn_s_barrier()
#define SCB() __builtin_amdgcn_sched_barrier(0)
#define VMW(n) { asm volatile("s_waitcnt vmcnt(" #n ")" ::: "memory"); SCB(); }

// ---------------- fp32 -> bf16 convert (vectorized, grid-stride) ----------
__global__ __launch_bounds__(256) void cvt_f32_bf16(const float* __restrict__ in,
                                                    ushort* __restrict__ out, int n4) {
    int i = blockIdx.x * 256 + threadIdx.x;
    int stride = gridDim.x * 256;
    for (; i < n4; i += stride) {
        float4 v = ((const float4*)in)[i];
        ushort4 o;
        o.x = f2bf(v.x); o.y = f2bf(v.y); o.z = f2bf(v.z); o.w = f2bf(v.w);
        ((ushort4*)out)[i] = o;
    }
}

// ---------------- RoPE cos/sin table: [2048][64] float2 ------------------
__global__ __launch_bounds__(256) void rope_table_k(float2* __restrict__ tab) {
    int idx = blockIdx.x * 256 + threadIdx.x;
    if (idx >= SS * 64) return;
    int j = idx & 63;
    int s = idx >> 6;
    float e = -(float)j * (13.287712379549449f / 64.0f);
    float inv = exp2f(e);
    float ang = (float)s * inv;
    float sv, cv;
    sincosf(ang, &sv, &cv);
    tab[idx] = make_float2(cv, sv);
}

// ---------------- RoPE apply in-place on bf16 QKV; emit fp32 K out -------
__global__ __launch_bounds__(256) void rope_apply_k(ushort* __restrict__ qkv,
                                                    const float2* __restrict__ tab,
                                                    float* __restrict__ kout) {
    int p = blockIdx.x * 256 + threadIdx.x;
    if (p >= NROWS * 2 * NHH * 64) return;
    int j  = p & 63;
    int h  = (p >> 6) & 15;
    int w  = (p >> 10) & 1;   // 0=q, 1=k
    int bs = p >> 11;
    int s  = bs & (SS - 1);
    size_t off = (size_t)bs * QKVN + (size_t)w * HIDD + h * HDD + 2 * j;
    u32 pr = *(const u32*)(qkv + off);
    float x1 = bf2f((ushort)(pr & 0xffffu));
    float x2 = bf2f((ushort)(pr >> 16));
    float2 cs = tab[s * 64 + j];
    float r1 = x1 * cs.x - x2 * cs.y;
    float r2 = x1 * cs.y + x2 * cs.x;
    if (w == 0) {            // fold score scale AND log2(e) into Q
        r1 *= SCALE_QL2; r2 *= SCALE_QL2;
    } else {                 // K: also write fp32 output (unscaled)
        float* ko = kout + ((size_t)bs * NHH + h) * HDD + 2 * j;
        ko[0] = r1; ko[1] = r2;
    }
    u32 op = (u32)f2bf(r1) | ((u32)f2bf(r2) << 16);
    *(u32*)(qkv + off) = op;
}

// ---------------- V transpose: qkv V section -> VT[b][h][d][s] -----------
__global__ __launch_bounds__(256) void vtrans_k(const ushort* __restrict__ qkv,
                                                ushort* __restrict__ vt) {
    __shared__ ushort tile[64 * 66];
    int bid = blockIdx.x;              // 2048 = 32 bh * 32 st * 2 dt
    int dt = bid & 1, st = (bid >> 1) & 31, bh = bid >> 6;
    int b = bh >> 4, h = bh & 15;
    int s0 = st * 64, d0 = dt * 64;
    int tid = threadIdx.x;
    #pragma unroll
    for (int i = 0; i < 2; ++i) {
        int idx = tid + i * 256;
        int row = idx >> 3, c8 = idx & 7;
        const ushort* src = qkv + (size_t)(b * SS + s0 + row) * QKVN + 2 * HIDD + h * HDD + d0 + c8 * 8;
        uint4 v = *(const uint4*)src;
        const u32* vw = (const u32*)&v;
        u32* dst = (u32*)((char*)tile + row * 132 + c8 * 16);
        dst[0] = vw[0]; dst[1] = vw[1]; dst[2] = vw[2]; dst[3] = vw[3];
    }
    __syncthreads();
    #pragma unroll
    for (int i = 0; i < 2; ++i) {
        int idx = tid + i * 256;
        int d = idx >> 3, sc8 = idx & 7;
        u32 wv[4];
        #pragma unroll
        for (int k = 0; k < 4; ++k) {
            ushort a = tile[(sc8 * 8 + 2 * k) * 66 + d];
            ushort c = tile[(sc8 * 8 + 2 * k + 1) * 66 + d];
            wv[k] = (u32)a | ((u32)c << 16);
        }
        ushort* dst = vt + ((size_t)(b * NHH + h) * HDD + d0 + d) * SS + s0 + sc8 * 8;
        *(uint4*)dst = *(const uint4*)wv;
    }
}

// ---------------- 128x256-tile GEMM, C = A * B^T, K=2048 -----------------
// v3: 3 LDS buffers (144KB), prefetch distance 2, vmcnt(6) -> load latency
// fully hidden (load->use = 2 iterations ~1000cyc). 8 waves 2Mx4N, BK=64,
// zero-conflict XOR swizzle, XCD-locality swizzle v2 (B panels L2-resident).
#define SA2(bb, kc) { const ushort* _s = Ab + (size_t)(kc) + off0; \
    GL_LDS(_s,            smem + (bb) * 49152 + w * 1024); \
    GL_LDS(_s + 64 * 2048, smem + (bb) * 49152 + 8192 + w * 1024); }
#define SB4(bb, kc) { const ushort* _s = Bb + (size_t)(kc) + off0; \
    GL_LDS(_s,             smem + (bb) * 49152 + 16384 + w * 1024); \
    GL_LDS(_s + 64 * 2048,  smem + (bb) * 49152 + 24576 + w * 1024); \
    GL_LDS(_s + 128 * 2048, smem + (bb) * 49152 + 32768 + w * 1024); \
    GL_LDS(_s + 192 * 2048, smem + (bb) * 49152 + 40960 + w * 1024); }
#define RDA(dst, bb, kk) { const char* _p = smem + (bb) * 49152 + aoff; \
    _Pragma("unroll") for (int f = 0; f < 4; ++f) \
        dst[f] = *(const s16x8*)(_p + f * 2048 + (colr ^ ((kk) << 6))); }
#define RDB(dst, bb, kk) { const char* _p = smem + (bb) * 49152 + 16384 + boff; \
    _Pragma("unroll") for (int n = 0; n < 4; ++n) \
        dst[n] = *(const s16x8*)(_p + n * 2048 + (colr ^ ((kk) << 6))); }
#define MMX(aa, bb2) { __builtin_amdgcn_s_setprio(1); \
    _Pragma("unroll") for (int f = 0; f < 4; ++f) \
        _Pragma("unroll") for (int n = 0; n < 4; ++n) \
            acc[f][n] = __builtin_amdgcn_mfma_f32_16x16x32_bf16( \
                aa[f], bb2[n], acc[f][n], 0, 0, 0); \
    __builtin_amdgcn_s_setprio(0); }

template<int OUTF32>
__global__ __launch_bounds__(512) void gemm128(const ushort* __restrict__ A,
                                               const ushort* __restrict__ Bm,
                                               void* __restrict__ Cv, int N) {
    __shared__ char smem[147456];                // 3 x 48KB buffers
    const int tid = threadIdx.x;
    const int w = tid >> 6, lane = tid & 63;
    const int wr = w >> 2, wc = w & 3;           // 2M x 4N waves
    const int l16 = lane & 15, lq = lane >> 4;

    // XCD-locality swizzle v2 (requires nbn % 8 == 0)
    const int nbn = N >> 8;                       // N-tiles (24 or 8)
    const int nbm = gridDim.x / nbn;              // M-tiles (32)
    const int cpx = nbn >> 3;                     // N-cols per XCD (3 or 1)
    const int xcd = blockIdx.x & 7;
    const int idx = blockIdx.x >> 3;              // 0 .. nbm*cpx-1
    const int bn_t = xcd * cpx + idx / nbm;
    const int bm_t = idx % nbm;
    const int bm0 = bm_t << 7, bn0 = bn_t << 8;

    const ushort* Ab = A + (size_t)bm0 * 2048;
    const ushort* Bb = Bm + (size_t)bn0 * 2048;

    // stage: rows chunk*64 + w*8 + (lane>>3), pre-swizzled column
    const int colu = ((lane & 7) ^ ((lane >> 3) & 7)) << 3;         // ushorts
    const u32 off0 = (u32)((w * 8 + (lane >> 3)) * 2048 + colu);
    // read addressing
    const int colr = (lq << 4) ^ ((l16 & 7) << 4);                  // bytes
    const int aoff = wr * 8192 + l16 * 128;
    const int boff = wc * 8192 + l16 * 128;

    f32x4 acc[4][4] = {};
    s16x8 a0[4], a1[4], b0[4], b1[4];

    // prologue: stage tiles 0,1 into buf0,buf1 (12 loads)
    SA2(0, 0); SB4(0, 0);
    SA2(1, 64); SB4(1, 64);

    int cur = 0, stb = 2;
    for (int t = 0; t < 32; ++t) {
        const int kcn = ((t + 2) & 31) * 64;
        VMW(6); BAR(); SCB();              // tile t's 6 loads drained
        RDA(a0, cur, 0); RDB(b0, cur, 0);
        RDA(a1, cur, 1); RDB(b1, cur, 1);  // 16 ds_reads
        SA2(stb, kcn); SB4(stb, kcn);      // stage t+2 (6 gloads, deep)
        MMX(a0, b0);                       // compiler inserts lgkm waits
        MMX(a1, b1);
        SCB(); BAR();                      // all waves done reading cur
        cur = (cur == 2) ? 0 : cur + 1;
        stb = (stb == 2) ? 0 : stb + 1;
    }

    // epilogue
    #pragma unroll
    for (int f = 0; f < 4; ++f)
        #pragma unroll
        for (int n = 0; n < 4; ++n) {
            int row = bm0 + wr * 64 + f * 16 + lq * 4;
            int col = bn0 + wc * 64 + n * 16 + l16;
            if (OUTF32) {
                float* C = (float*)Cv;
                #pragma unroll
                for (int r = 0; r < 4; ++r)
                    C[(size_t)(row + r) * N + col] = acc[f][n][r];
            } else {
                ushort* C = (ushort*)Cv;
                #pragma unroll
                for (int r = 0; r < 4; ++r)
                    C[(size_t)(row + r) * N + col] = f2bf(acc[f][n][r]);
            }
        }
}

// ---------------- Flash attention (v3: log2 softmax, defer-max, cvt_pk) --
__global__ __launch_bounds__(256, 2) void attn_k(const ushort* __restrict__ qkv,
                                                 const ushort* __restrict__ vt,
                                                 ushort* __restrict__ aout) {
    extern __shared__ char asmem[];

    const int bid = blockIdx.x;
    const int L = (bid & 7) * 64 + (bid >> 3);
    const int qt = L & 15, bh = L >> 4;
    const int b = bh >> 4, h = bh & 15;
    const int tid = threadIdx.x;
    const int w = tid >> 6, lane = tid & 63;
    const int l16 = lane & 15, lq = lane >> 4;

    s16x8 qf[2][4];
    #pragma unroll
    for (int qb = 0; qb < 2; ++qb) {
        size_t qbase = (size_t)(b * SS + qt * 128 + w * 32 + qb * 16 + l16) * QKVN + h * HDD;
        #pragma unroll
        for (int kk = 0; kk < 4; ++kk)
            qf[qb][kk] = *(const s16x8*)(qkv + qbase + kk * 32 + lq * 8);
    }

    const ushort* ksrc[4];
    const ushort* vsrc[4];
    #pragma unroll
    for (int i = 0; i < 4; ++i) {
        int krow = w * 16 + i * 4 + (lane >> 4);
        int kcolb = ((lane & 15) * 16) ^ ((krow & 7) << 4);
        ksrc[i] = qkv + (size_t)(b * SS + krow) * QKVN + HIDD + h * HDD + kcolb / 2;
        int drow = w * 32 + i * 8 + (lane >> 3);
        int vcolb = ((lane & 7) * 16) ^ ((drow & 7) << 4);
        vsrc[i] = vt + ((size_t)(b * NHH + h) * HDD + drow) * SS + vcolb / 2;
    }

    f32x4 accO[2][8] = {};
    float mrow[2] = {-3e38f, -3e38f};
    float lrow[2] = {0.f, 0.f};

    char* Pb = asmem + 65536 + w * 4096;
    const int kswz = (l16 & 7) << 4;
    const int pswz = (l16 & 3) << 5;

    {
        char* kb = asmem + w * 4096;
        char* vb = asmem + 32768 + w * 4096;
        #pragma unroll
        for (int i = 0; i < 4; ++i) {
            GL_LDS(ksrc[i], kb + i * 1024); ksrc[i] += 64 * QKVN;
            GL_LDS(vsrc[i], vb + i * 1024); vsrc[i] += 64;
        }
    }
    __syncthreads();

    for (int t = 0; t < 32; ++t) {
        const int cur = t & 1;
        if (t < 31) {
            char* kb = asmem + (cur ^ 1) * 16384 + w * 4096;
            char* vb = asmem + 32768 + (cur ^ 1) * 16384 + w * 4096;
            #pragma unroll
            for (int i = 0; i < 4; ++i) {
                GL_LDS(ksrc[i], kb + i * 1024); ksrc[i] += 64 * QKVN;
                GL_LDS(vsrc[i], vb + i * 1024); vsrc[i] += 64;
            }
        }
        const char* Kb = asmem + cur * 16384;
        const char* Vb = asmem + 32768 + cur * 16384;

        // S^T = K . Q  (scores already in log2 domain via Q pre-scale)
        f32x4 sc[2][4] = {};
        #pragma unroll
        for (int nb = 0; nb < 4; ++nb) {
            int rbase = (nb * 16 + l16) * 256;
            #pragma unroll
            for (int kk = 0; kk < 4; ++kk) {
                s16x8 kf = *(const s16x8*)(Kb + rbase + ((kk * 64 + lq * 16) ^ kswz));
                sc[0][nb] = __builtin_amdgcn_mfma_f32_16x16x32_bf16(kf, qf[0][kk], sc[0][nb], 0, 0, 0);
                sc[1][nb] = __builtin_amdgcn_mfma_f32_16x16x32_bf16(kf, qf[1][kk], sc[1][nb], 0, 0, 0);
            }
        }

        // online softmax with defer-max (T13): row = q = qb*16+l16
        float pmax[2];
        #pragma unroll
        for (int qb = 0; qb < 2; ++qb) {
            float m0 = fmaxf(fmaxf(fmaxf(sc[qb][0][0], sc[qb][0][1]), fmaxf(sc[qb][0][2], sc[qb][0][3])),
                             fmaxf(fmaxf(sc[qb][1][0], sc[qb][1][1]), fmaxf(sc[qb][1][2], sc[qb][1][3])));
            m0 = fmaxf(m0, fmaxf(fmaxf(fmaxf(sc[qb][2][0], sc[qb][2][1]), fmaxf(sc[qb][2][2], sc[qb][2][3])),
                                 fmaxf(fmaxf(sc[qb][3][0], sc[qb][3][1]), fmaxf(sc[qb][3][2], sc[qb][3][3]))));
            m0 = fmaxf(m0, __shfl_xor(m0, 16));
            m0 = fmaxf(m0, __shfl_xor(m0, 32));
            pmax[qb] = m0;
        }
        #pragma unroll
        for (int qb = 0; qb < 2; ++qb) {
            if (__all(pmax[qb] - mrow[qb] <= 8.0f)) {
                float mm = mrow[qb];
                float s = 0.f;
                #pragma unroll
                for (int nb = 0; nb < 4; ++nb)
                    #pragma unroll
                    for (int r = 0; r < 4; ++r) {
                        float pv = EXP2(sc[qb][nb][r] - mm);
                        sc[qb][nb][r] = pv;
                        s += pv;
                    }
                s += __shfl_xor(s, 16);
                s += __shfl_xor(s, 32);
                lrow[qb] += s;
            } else {
                float mnew = fmaxf(mrow[qb], pmax[qb]);
                float sclv = EXP2(mrow[qb] - mnew);
                mrow[qb] = mnew;
                float s = 0.f;
                #pragma unroll
                for (int nb = 0; nb < 4; ++nb)
                    #pragma unroll
                    for (int r = 0; r < 4; ++r) {
                        float pv = EXP2(sc[qb][nb][r] - mnew);
                        sc[qb][nb][r] = pv;
                        s += pv;
                    }
                s += __shfl_xor(s, 16);
                s += __shfl_xor(s, 32);
                lrow[qb] = lrow[qb] * sclv + s;
                #pragma unroll
                for (int r = 0; r < 4; ++r) {
                    float sr = __shfl(sclv, lq * 4 + r);
                    #pragma unroll
                    for (int ob = 0; ob < 8; ++ob)
                        accO[qb][ob][r] *= sr;
                }
            }
        }

        // P -> per-wave swizzled LDS via v_cvt_pk_bf16_f32
        #pragma unroll
        for (int qb = 0; qb < 2; ++qb) {
            int qrow = (qb * 16 + l16) * 128;
            #pragma unroll
            for (int nb = 0; nb < 4; ++nb) {
                uint2 v2 = make_uint2(cvtpk(sc[qb][nb][0], sc[qb][nb][1]),
                                      cvtpk(sc[qb][nb][2], sc[qb][nb][3]));
                *(uint2*)(Pb + qrow + ((nb * 32 + lq * 8) ^ pswz)) = v2;
            }
        }

        // O += P . V
        #pragma unroll
        for (int kk2 = 0; kk2 < 2; ++kk2) {
            int cb = (kk2 * 64 + lq * 16);
            s16x8 pf0 = *(const s16x8*)(Pb + l16 * 128 + (cb ^ pswz));
            s16x8 pf1 = *(const s16x8*)(Pb + (16 + l16) * 128 + (cb ^ pswz));
            #pragma unroll
            for (int ob = 0; ob < 8; ++ob) {
                int d = ob * 16 + l16;
                s16x8 vf = *(const s16x8*)(Vb + d * 128 + (cb ^ ((d & 7) << 4)));
                accO[0][ob] = __builtin_amdgcn_mfma_f32_16x16x32_bf16(pf0, vf, accO[0][ob], 0, 0, 0);
                accO[1][ob] = __builtin_amdgcn_mfma_f32_16x16x32_bf16(pf1, vf, accO[1][ob], 0, 0, 0);
            }
        }
        __syncthreads();
    }

    float inv0 = 1.f / lrow[0], inv1 = 1.f / lrow[1];
    #pragma unroll
    for (int r = 0; r < 4; ++r) {
        float i0 = __shfl(inv0, lq * 4 + r);
        float i1 = __shfl(inv1, lq * 4 + r);
        int row0 = b * SS + qt * 128 + w * 32 + lq * 4 + r;
        #pragma unroll
        for (int ob = 0; ob < 8; ++ob) {
            int col = h * HDD + ob * 16 + l16;
            aout[(size_t)row0 * HIDD + col] = f2bf(accO[0][ob][r] * i0);
            aout[(size_t)(row0 + 16) * HIDD + col] = f2bf(accO[1][ob][r] * i1);
        }
    }
}

// ---------------- launch -------------------------------------------------
extern "C" void kernel_launch(void* const* d_in, const int* in_sizes, int n_in,
                              void* d_out, int out_size, void* d_ws, size_t ws_size,
                              hipStream_t stream) {
    const float* x     = (const float*)d_in[0];
    const float* w_qkv = (const float*)d_in[1];
    const float* w_out = (const float*)d_in[2];
    float* out = (float*)d_out;

    char* ws = (char*)d_ws;
    ushort* qkv_bf  = (ushort*)(ws);
    ushort* xbf     = (ushort*)(ws + 50331648);
    ushort* wq_bf   = (ushort*)(ws + 67108864);
    ushort* vtbuf   = (ushort*)(ws + 67108864);
    ushort* wout_bf = (ushort*)(ws + 67108864 + 16777216);
    float2* tab     = (float2*)(ws + 92274688);

    cvt_f32_bf16<<<2048, 256, 0, stream>>>(x, xbf, (NROWS * HIDD) / 4);
    cvt_f32_bf16<<<2048, 256, 0, stream>>>(w_qkv, wq_bf, (QKVN * HIDD) / 4);
    rope_table_k<<<(SS * 64) / 256, 256, 0, stream>>>(tab);

    // QKV projection: 128x256 tiles -> 32*24 = 768 blocks (3/CU exact)
    gemm128<0><<<(NROWS / 128) * (QKVN / 256), 512, 0, stream>>>(xbf, wq_bf, qkv_bf, QKVN);

    rope_apply_k<<<(NROWS * 2 * NHH * 64) / 256, 256, 0, stream>>>(qkv_bf, tab,
                                                                   out + (size_t)NROWS * HIDD);
    vtrans_k<<<2048, 256, 0, stream>>>(qkv_bf, vtbuf);
    cvt_f32_bf16<<<2048, 256, 0, stream>>>(w_out, wout_bf, (HIDD * HIDD) / 4);

    attn_k<<<512, 256, 81920, stream>>>(qkv_bf, vtbuf, xbf);

    // output projection: 32*8 = 256 blocks (1/CU exact), fp32 out
    gemm128<1><<<(NROWS / 128) * (HIDD / 256), 512, 0, stream>>>(xbf, wout_bf, out, HIDD);
}